// Round 7
// baseline (39.123 us; speedup 1.0000x reference)
//
#include <hip/hip_runtime.h>
#include <hip/hip_bf16.h>

typedef short bf16x8 __attribute__((ext_vector_type(8)));
typedef float f32x16 __attribute__((ext_vector_type(16)));
typedef unsigned short u16;

#define B 128
#define LQ 32
#define LK 128
#define D 128

// ws layout:
//   lbf: fragment-ordered l, [x][ks(8)][hh(2)][rr(32)] x 16B = 8 KB/x, 1 MiB
//   rbf: fragment-ordered r, [y][mj(4)][ks(8)][hh(2)][rr(32)] x 16B = 32 KB/y, 4 MiB
//   sims: B*B f32 (64 KiB)
// 32x32x16 MFMA fragment: lane = hh*32 + rr holds 8 elems, k = ks*16+hh*8+e;
// rr = A-row / B-col. Verified by rounds 3-5 (absmax 0).

static __device__ inline u16 f2bf_rne(float f) {
  union { float f; unsigned u; } v; v.f = f;
  unsigned r = v.u + 0x7fffu + ((v.u >> 16) & 1u);
  return (u16)(r >> 16);
}

// One wave per row. Normalize, cast to bf16, store in MFMA-fragment order.
__global__ __launch_bounds__(256) void normalize_kernel(
    const float* __restrict__ left, const float* __restrict__ right,
    char* __restrict__ lbf, char* __restrict__ rbf) {
  int wave = (blockIdx.x * blockDim.x + threadIdx.x) >> 6;
  int lane = threadIdx.x & 63;
  const int n_l = B * LQ;
  const float* src; char* dst;
  if (wave < n_l) {
    src = left + (size_t)wave * D;
    dst = lbf + (wave >> 5) * 8192 + (wave & 31) * 16;
  } else {
    int row = wave - n_l;
    src = right + (size_t)row * D;
    dst = rbf + (row >> 7) * 32768 + ((row >> 5) & 3) * 8192 + (row & 31) * 16;
  }
  float2 v = *reinterpret_cast<const float2*>(src + lane * 2);
  float ss = v.x * v.x + v.y * v.y;
#pragma unroll
  for (int off = 1; off < 64; off <<= 1) ss += __shfl_xor(ss, off);
  float inv = 1.0f / fmaxf(sqrtf(ss), 1e-12f);
  unsigned packed = (unsigned)f2bf_rne(v.x * inv) |
                    ((unsigned)f2bf_rne(v.y * inv) << 16);
  *reinterpret_cast<unsigned*>(
      dst + (lane >> 3) * 1024 + ((lane >> 2) & 1) * 512 + (lane & 3) * 4) = packed;
}

// Thin-wave maxsim: wave = ONE x, block = 4 x's, 4 y's. 1024 blocks at
// 4 blocks/CU (launch_bounds(256,4) -> <=128 VGPR) = 4 waves/SIMD: 2x the
// outstanding loads of rounds 3-5. XCD swizzle: xcd = bid&7 owns yg in
// {4*xcd..4*xcd+3} -> 16 y-tiles (512KB) + lbf (1MB) L2-local per XCD.
__global__ __launch_bounds__(256, 4) void maxsim_kernel(
    const char* __restrict__ lbf, const char* __restrict__ rbf,
    float* __restrict__ sims) {
  const int lane = threadIdx.x & 63;
  const int wv   = threadIdx.x >> 6;     // 0..3
  const int bid  = blockIdx.x;           // 0..1023
  const int xcd  = bid & 7;
  const int w    = bid >> 3;             // 0..127
  const int yg   = xcd * 4 + (w & 3);    // 0..31
  const int xg   = w >> 2;               // 0..31
  const int x    = xg * 4 + wv;
  const int lane16 = lane * 16;

  // B fragments for this wave's x: 8 contiguous 1KB loads.
  bf16x8 bfr[8];
#pragma unroll
  for (int ks = 0; ks < 8; ++ks)
    bfr[ks] = *reinterpret_cast<const bf16x8*>(
        lbf + x * 8192 + ks * 1024 + lane16);

  const char* rb0 = rbf + (size_t)yg * 4 * 32768;  // 4 y-tiles, contiguous

  // step s = 0..15: y = s>>2, mj = s&3; A-subtile at rb0 + s*8192.
#define LOADA(dst, s_next)                                                   \
  {                                                                          \
    const char* nb = rb0 + (s_next) * 8192;                                  \
    _Pragma("unroll")                                                        \
    for (int ks = 0; ks < 8; ++ks)                                           \
      dst[ks] = *reinterpret_cast<const bf16x8*>(nb + ks * 1024 + lane16);   \
  }

#define MFMA8(srcA)                                                          \
  __builtin_amdgcn_s_setprio(1);                                             \
  _Pragma("unroll")                                                          \
  for (int t = 0; t < 16; ++t) acc[t] = 0.f;                                 \
  _Pragma("unroll")                                                          \
  for (int ks = 0; ks < 8; ++ks)                                             \
    acc = __builtin_amdgcn_mfma_f32_32x32x16_bf16(srcA[ks], bfr[ks], acc,    \
                                                  0, 0, 0);                  \
  __builtin_amdgcn_s_setprio(0);

  bf16x8 pA[8], pB[8];
  f32x16 acc;
  LOADA(pA, 0);

#pragma unroll
  for (int yy = 0; yy < 4; ++yy) {
    float cm = -3.0e38f;
#pragma unroll
    for (int mj = 0; mj < 4; ++mj) {
      const int s = yy * 4 + mj;        // compile-time after unroll
      if ((s & 1) == 0) {
        if (s < 15) LOADA(pB, s + 1);
        MFMA8(pA);
      } else {
        if (s < 15) LOADA(pA, s + 1);
        MFMA8(pB);
      }
      // 16 regs = 16 distinct j-rows: fold into running column max
#pragma unroll
      for (int t = 0; t < 16; t += 4)
        cm = fmaxf(cm, fmaxf(fmaxf(acc[t], acc[t + 1]),
                             fmaxf(acc[t + 2], acc[t + 3])));
    }
    // lanes l, l+32 hold complementary row sets -> xor32 completes max_j;
    // butterfly-sum 32 column-maxes (i = lane&31).
    cm = fmaxf(cm, __shfl_xor(cm, 32));
#pragma unroll
    for (int off = 1; off <= 16; off <<= 1) cm += __shfl_xor(cm, off);
    if (lane == 0) sims[x * B + (yg * 4 + yy)] = cm;
  }
#undef LOADA
#undef MFMA8
}

// log-softmax + CE. 1 block, 1024 threads = 16 waves; wave w -> rows w*8..+7.
__global__ __launch_bounds__(1024) void loss_kernel(
    const float* __restrict__ sims, const float* __restrict__ logit_scale,
    const int* __restrict__ pos_idx, float* __restrict__ out) {
  __shared__ float red[16];
  const int lane = threadIdx.x & 63;
  const int wv   = threadIdx.x >> 6;
  const float scale = expf(logit_scale[0]);
  float local = 0.f;
#pragma unroll
  for (int rr = 0; rr < 8; ++rr) {
    const int x = wv * 8 + rr;
    const float* row = sims + x * B;
    float a = row[lane], b2 = row[64 + lane];
    float m = fmaxf(a, b2);
#pragma unroll
    for (int off = 1; off < 64; off <<= 1) m = fmaxf(m, __shfl_xor(m, off));
    float ml = scale * m;
    float e = expf(scale * a - ml) + expf(scale * b2 - ml);
#pragma unroll
    for (int off = 1; off < 64; off <<= 1) e += __shfl_xor(e, off);
    int pos = pos_idx[x];
    float pv = __shfl(pos < 64 ? a : b2, pos & 63);
    local += -(scale * pv - ml - logf(e));
  }
  if (lane == 0) red[wv] = local;
  __syncthreads();
  if (threadIdx.x == 0) {
    float t = 0.f;
#pragma unroll
    for (int i = 0; i < 16; ++i) t += red[i];
    out[0] = t / (float)B;
  }
}

extern "C" void kernel_launch(void* const* d_in, const int* in_sizes, int n_in,
                              void* d_out, int out_size, void* d_ws, size_t ws_size,
                              hipStream_t stream) {
  const float* left  = (const float*)d_in[0];
  const float* right = (const float*)d_in[1];
  const float* ls    = (const float*)d_in[2];
  const int*   pos   = (const int*)d_in[3];
  float* out = (float*)d_out;

  char* ws  = (char*)d_ws;
  char* lbf = ws;                                   // 1 MiB
  char* rbf = ws + (size_t)(1 << 20);               // 4 MiB
  float* sims = (float*)(ws + (size_t)(5 << 20));   // 64 KiB

  int waves = B * LQ + B * LK;  // 20480 rows
  normalize_kernel<<<waves / 4, 256, 0, stream>>>(left, right, lbf, rbf);
  maxsim_kernel<<<1024, 256, 0, stream>>>(lbf, rbf, sims);
  loss_kernel<<<1, 1024, 0, stream>>>(sims, ls, pos, out);
}